// Round 5
// baseline (2432.348 us; speedup 1.0000x reference)
//
#include <hip/hip_runtime.h>

#define N_ATOMS 100000
#define N_BONDS 200000
#define NEI 6
#define ITERS 6

#define MB_PAD 200064   // 1563*128
#define MA_PAD 100096   // 782*128
#define MT_B 1563
#define MT_A 782
#define KL 320          // final K (287 padded to 320)

typedef __bf16 bf16x8 __attribute__((ext_vector_type(8)));
typedef float f32x4 __attribute__((ext_vector_type(4)));

__device__ __forceinline__ float b2f(unsigned short u) {
  union { unsigned int i; float f; } x; x.i = ((unsigned int)u) << 16; return x.f;
}
__device__ __forceinline__ unsigned short f2b(float f) {
  union { float f; unsigned int i; } x; x.f = f;
  unsigned int r = (x.i + 0x7FFFu + ((x.i >> 16) & 1u)) >> 16;
  return (unsigned short)r;
}
__device__ __forceinline__ float lrelu(float v) { return v > 0.f ? v : 0.1f * v; }

// ---------------------------------------------------------------------------
// Weight pack: float32 in -> bf16 B^T copies (row-major [N,K]).
// wkT/wvT/wqT [256][256]; wmsgT [256][128] (k<64: Wout, 64..100: Wemb, pad 0)
// wlastT [256][320] (k<256: W_last[31+k], 256..286: W_last[k-256], pad 0)
// ---------------------------------------------------------------------------
__global__ __launch_bounds__(256) void pack_weights(
    const float* __restrict__ Wq, const float* __restrict__ Wk,
    const float* __restrict__ Wv, const float* __restrict__ Wemb,
    const float* __restrict__ Wout, const float* __restrict__ Wlast,
    unsigned short* __restrict__ wkT, unsigned short* __restrict__ wvT,
    unsigned short* __restrict__ wqT, unsigned short* __restrict__ wmsgT,
    unsigned short* __restrict__ wlastT)
{
  int t = blockIdx.x * 256 + threadIdx.x;   // grid = 320 blocks -> t < 81920
  if (t < 65536) {
    int n = t >> 8, k = t & 255;
    wkT[t] = f2b(Wk[k * 256 + n]);
    wvT[t] = f2b(Wv[k * 256 + n]);
    wqT[t] = f2b(Wq[k * 256 + n]);
  }
  if (t < 32768) {
    int n = t >> 7, k = t & 127;
    float v = 0.f;
    if (k < 64)       v = Wout[k * 256 + n];
    else if (k < 101) v = Wemb[(k - 64) * 256 + n];
    wmsgT[t] = f2b(v);
  }
  {
    int n = t / KL, k = t % KL;
    float v = 0.f;
    if (k < 256)      v = Wlast[(31 + k) * 256 + n];
    else if (k < 287) v = Wlast[(k - 256) * 256 + n];
    wlastT[t] = f2b(v);
  }
}

// A2 [MB_PAD][128]: cols 0..63 = 0 (att slot), 64..100 = bf16(fbonds), rest 0
__global__ __launch_bounds__(256) void pack_bonds(
    const float* __restrict__ fbonds, unsigned short* __restrict__ A2)
{
  int t = blockIdx.x * 256 + threadIdx.x;
  int r = t >> 7, c = t & 127;
  float v = 0.f;
  if (c >= 64 && c < 101 && r < N_BONDS) v = fbonds[r * 37 + (c - 64)];
  A2[t] = f2b(v);
}

// ---------------------------------------------------------------------------
// m97-style 128x128 bf16 GEMM. A [*,K] row-major bf16, BT [N,K] row-major bf16.
// Staging: lane l of wave w loads row mBase+r*32+w*8+(l>>3), cols k0+(l&7)*8
// -> As + r*2048 + w*512 + l*8 (wave-uniform LDS base + lane*16B).
// EP: 0 plain bf16 store; 1 +bias Xf[col] leaky -> bf16;
//     3 +bias Xf[col] leaky, row<Mreal guard -> FLOAT out
// ---------------------------------------------------------------------------
template<int EP>
__global__ __launch_bounds__(256) void gemm_bt(
    const unsigned short* __restrict__ A,
    const unsigned short* __restrict__ BT,
    unsigned short* __restrict__ C0,
    float* __restrict__ Fout,
    const float* __restrict__ Xf,
    int K, int N, int Mreal)
{
  __shared__ __align__(16) unsigned short As[128 * 64];
  __shared__ __align__(16) unsigned short Bs[128 * 64];
  const int tid  = threadIdx.x;
  const int wave = tid >> 6, lane = tid & 63;
  const int wr = wave >> 1, wc = wave & 1;
  const int lhi = lane >> 4, llo = lane & 15;
  const int mBase = blockIdx.x * 128;
  const int nBase = blockIdx.y * 128;
  const int crow = tid >> 3, ccol = tid & 7;   // per-lane staging coords

  f32x4 acc[4][4];
  #pragma unroll
  for (int i = 0; i < 4; ++i)
    #pragma unroll
    for (int j = 0; j < 4; ++j)
      acc[i][j] = f32x4{0.f, 0.f, 0.f, 0.f};

  for (int k0 = 0; k0 < K; k0 += 64) {
    __syncthreads();
    #pragma unroll
    for (int r = 0; r < 4; ++r) {
      const unsigned short* ga =
          A + (size_t)(mBase + r * 32 + crow) * K + (k0 + ccol * 8);
      __builtin_amdgcn_global_load_lds(
          (const __attribute__((address_space(1))) void*)ga,
          (__attribute__((address_space(3))) void*)(As + r * 2048 + wave * 512), 16, 0, 0);
      const unsigned short* gb =
          BT + (size_t)(nBase + r * 32 + crow) * K + (k0 + ccol * 8);
      __builtin_amdgcn_global_load_lds(
          (const __attribute__((address_space(1))) void*)gb,
          (__attribute__((address_space(3))) void*)(Bs + r * 2048 + wave * 512), 16, 0, 0);
    }
    __syncthreads();
    #pragma unroll
    for (int ks = 0; ks < 2; ++ks) {
      bf16x8 af[4], bfv[4];
      #pragma unroll
      for (int i = 0; i < 4; ++i)
        af[i] = *reinterpret_cast<const bf16x8*>(&As[(wr * 64 + i * 16 + llo) * 64 + ks * 32 + lhi * 8]);
      #pragma unroll
      for (int j = 0; j < 4; ++j)
        bfv[j] = *reinterpret_cast<const bf16x8*>(&Bs[(wc * 64 + j * 16 + llo) * 64 + ks * 32 + lhi * 8]);
      #pragma unroll
      for (int i = 0; i < 4; ++i)
        #pragma unroll
        for (int j = 0; j < 4; ++j)
          acc[i][j] = __builtin_amdgcn_mfma_f32_16x16x32_bf16(af[i], bfv[j], acc[i][j], 0, 0, 0);
    }
  }

  #pragma unroll
  for (int i = 0; i < 4; ++i) {
    #pragma unroll
    for (int j = 0; j < 4; ++j) {
      const int col = nBase + wc * 64 + j * 16 + llo;
      #pragma unroll
      for (int r = 0; r < 4; ++r) {
        const int row = mBase + wr * 64 + i * 16 + lhi * 4 + r;
        const float v = acc[i][j][r];
        const size_t off = (size_t)row * N + col;
        if (EP == 0) {
          C0[off] = f2b(v);
        } else if (EP == 1) {
          C0[off] = f2b(lrelu(v + Xf[col]));
        } else {
          if (row < Mreal) Fout[off] = lrelu(v + Xf[col]);
        }
      }
    }
  }
}

// ---------------------------------------------------------------------------
// Pass 1: scores + softmax. One wave per bond (row chunk [rowOff, ...)).
// q row [256] head-major; kbuf row [256]. lane l: head h=l>>4, dims l*4..l*4+3.
// Stores normalized attn weights bf16 -> attnw[b][h*6+n].
// ---------------------------------------------------------------------------
__global__ __launch_bounds__(256) void score_kernel(
    const unsigned short* __restrict__ q,
    const unsigned short* __restrict__ kbuf,
    const int* __restrict__ bgraph,
    unsigned short* __restrict__ attnw,
    int rowOff)
{
  const int wid  = rowOff + blockIdx.x * 4 + (threadIdx.x >> 6);
  const int lane = threadIdx.x & 63;
  if (wid >= N_BONDS) return;

  const ushort4 qu = *reinterpret_cast<const ushort4*>(
      q + (size_t)(wid - rowOff) * 256 + lane * 4);
  const float q0 = b2f(qu.x), q1 = b2f(qu.y), q2 = b2f(qu.z), q3 = b2f(qu.w);

  float sc[NEI];
  #pragma unroll
  for (int n = 0; n < NEI; ++n) {
    const int bn = bgraph[wid * NEI + n];
    const ushort4 ku = *reinterpret_cast<const ushort4*>(
        kbuf + (size_t)bn * 256 + lane * 4);
    float p = q0 * b2f(ku.x) + q1 * b2f(ku.y) + q2 * b2f(ku.z) + q3 * b2f(ku.w);
    p += __shfl_xor(p, 1); p += __shfl_xor(p, 2);
    p += __shfl_xor(p, 4); p += __shfl_xor(p, 8);   // sum over 16-lane head group
    sc[n] = p * 0.125f + (bn != 0 ? 0.f : -1e7f);
  }
  float m = sc[0];
  #pragma unroll
  for (int n = 1; n < NEI; ++n) m = fmaxf(m, sc[n]);
  float e[NEI], s = 0.f;
  #pragma unroll
  for (int n = 0; n < NEI; ++n) { e[n] = __expf(sc[n] - m); s += e[n]; }
  const float inv = 1.f / s;

  const int n = lane & 15;
  float w = e[0];
  if (n == 1) w = e[1]; else if (n == 2) w = e[2]; else if (n == 3) w = e[3];
  else if (n == 4) w = e[4]; else if (n == 5) w = e[5];
  if (n < NEI)
    attnw[(size_t)wid * 24 + (lane >> 4) * NEI + n] = f2b(w * inv);
}

// ---------------------------------------------------------------------------
// Pass 2: weighted V + head-mean -> A2[b][0..63]. One wave per bond.
// ---------------------------------------------------------------------------
__global__ __launch_bounds__(256) void weighted_v(
    const unsigned short* __restrict__ vbuf,
    const unsigned short* __restrict__ attnw,
    const int* __restrict__ bgraph,
    unsigned short* __restrict__ A2)
{
  const int wid  = blockIdx.x * 4 + (threadIdx.x >> 6);
  const int lane = threadIdx.x & 63;
  if (wid >= N_BONDS) return;
  const int h = lane >> 4;
  float o0 = 0, o1 = 0, o2 = 0, o3 = 0;
  #pragma unroll
  for (int n = 0; n < NEI; ++n) {
    const int bn = bgraph[wid * NEI + n];
    const float a = b2f(attnw[(size_t)wid * 24 + h * NEI + n]);
    const ushort4 vu = *reinterpret_cast<const ushort4*>(
        vbuf + (size_t)bn * 256 + lane * 4);
    o0 += a * b2f(vu.x); o1 += a * b2f(vu.y);
    o2 += a * b2f(vu.z); o3 += a * b2f(vu.w);
  }
  o0 += __shfl_xor(o0, 16); o0 += __shfl_xor(o0, 32);
  o1 += __shfl_xor(o1, 16); o1 += __shfl_xor(o1, 32);
  o2 += __shfl_xor(o2, 16); o2 += __shfl_xor(o2, 32);
  o3 += __shfl_xor(o3, 16); o3 += __shfl_xor(o3, 32);
  if (lane < 16) {
    ushort4 ov;
    ov.x = f2b(o0 * 0.25f); ov.y = f2b(o1 * 0.25f);
    ov.z = f2b(o2 * 0.25f); ov.w = f2b(o3 * 0.25f);
    *reinterpret_cast<ushort4*>(A2 + (size_t)wid * 128 + lane * 4) = ov;
  }
}

// One wave per atom: nei_sum (fp32 accum) -> apad [MA_PAD][320]
// = [nei_sum(256) | bf16(fatoms)(31) | zeros]
__global__ __launch_bounds__(256) void atom_gather(
    const unsigned short* __restrict__ msg,
    const int* __restrict__ agraph,
    const float* __restrict__ fatoms,
    unsigned short* __restrict__ apad)
{
  const int aid  = blockIdx.x * 4 + (threadIdx.x >> 6);
  const int lane = threadIdx.x & 63;
  if (aid >= N_ATOMS) return;
  float s0 = 0, s1 = 0, s2 = 0, s3 = 0;
  #pragma unroll
  for (int n = 0; n < NEI; ++n) {
    const int b = agraph[aid * NEI + n];
    const ushort4 u = *reinterpret_cast<const ushort4*>(msg + (size_t)b * 256 + lane * 4);
    s0 += b2f(u.x); s1 += b2f(u.y); s2 += b2f(u.z); s3 += b2f(u.w);
  }
  ushort4 ov; ov.x = f2b(s0); ov.y = f2b(s1); ov.z = f2b(s2); ov.w = f2b(s3);
  *reinterpret_cast<ushort4*>(apad + (size_t)aid * KL + lane * 4) = ov;
  apad[(size_t)aid * KL + 256 + lane] =
      (lane < 31) ? f2b(fatoms[(size_t)aid * 31 + lane]) : (unsigned short)0;
}

// Diagnostic: zero output, out[0] = 10000 + ws_MB (distinguishable absmax)
__global__ __launch_bounds__(256) void diag_out(float* out, int n, float code) {
  int t = blockIdx.x * 256 + threadIdx.x;
  if (t < n) out[t] = (t == 0) ? code : 0.f;
}

extern "C" void kernel_launch(void* const* d_in, const int* in_sizes, int n_in,
                              void* d_out, int out_size, void* d_ws, size_t ws_size,
                              hipStream_t stream) {
  const float* fatoms = (const float*)d_in[0];
  const float* fbonds = (const float*)d_in[1];
  const int* agraph   = (const int*)d_in[2];
  const int* bgraph   = (const int*)d_in[3];
  // d_in[4] lig_scope: unused by the reference computation
  const float* Wemb   = (const float*)d_in[5];
  const float* bemb   = (const float*)d_in[6];
  const float* Wq     = (const float*)d_in[7];
  const float* Wk     = (const float*)d_in[8];
  const float* Wv     = (const float*)d_in[9];
  const float* Wout   = (const float*)d_in[10];
  const float* Wlast  = (const float*)d_in[11];
  const float* blast  = (const float*)d_in[12];
  float* out          = (float*)d_out;

  char* ws = (char*)d_ws;
  size_t off = 0;
  auto alloc = [&](size_t bytes) {
    char* p = ws + off; off += (bytes + 511) & ~(size_t)511; return p;
  };
  unsigned short* msg    = (unsigned short*)alloc((size_t)MB_PAD * 256 * 2);
  unsigned short* kv     = (unsigned short*)alloc((size_t)MB_PAD * 256 * 2); // K then V; atom-A alias
  unsigned short* A2     = (unsigned short*)alloc((size_t)MB_PAD * 128 * 2);
  unsigned short* attnw  = (unsigned short*)alloc((size_t)MB_PAD * 24 * 2);
  unsigned short* wkT    = (unsigned short*)alloc((size_t)256 * 256 * 2);
  unsigned short* wvT    = (unsigned short*)alloc((size_t)256 * 256 * 2);
  unsigned short* wqT    = (unsigned short*)alloc((size_t)256 * 256 * 2);
  unsigned short* wmsgT  = (unsigned short*)alloc((size_t)256 * 128 * 2);
  unsigned short* wlastT = (unsigned short*)alloc((size_t)256 * KL * 2);
  unsigned short* apad   = kv;   // alias: kv dead after the iteration loop (64 MB <= 102 MB)

  // adaptive Q chunk from leftover workspace
  long long remain = (long long)ws_size - (long long)off;
  int qrows = 0;
  if (remain >= 128 * 512) {
    long long r = remain / 512;           // bytes per q row = 256*2
    if (r > MB_PAD) r = MB_PAD;
    qrows = (int)(r & ~127LL);
  }
  unsigned short* q = (unsigned short*)(ws + off);

  if (qrows < 128) {   // workspace too small: diagnostic
    diag_out<<<dim3((out_size + 255) / 256), dim3(256), 0, stream>>>(
        out, out_size, 10000.f + (float)(ws_size >> 20));
    return;
  }

  pack_weights<<<dim3(320), dim3(256), 0, stream>>>(
      Wq, Wk, Wv, Wemb, Wout, Wlast, wkT, wvT, wqT, wmsgT, wlastT);
  pack_bonds<<<dim3(MB_PAD * 128 / 256), dim3(256), 0, stream>>>(fbonds, A2);

  // initial message: att cols of A2 are zero -> msg = leaky(fbonds@Wemb + b)
  gemm_bt<1><<<dim3(MT_B, 2), dim3(256), 0, stream>>>(
      A2, wmsgT, msg, (float*)nullptr, bemb, 128, 256, MB_PAD);

  for (int it = 0; it < ITERS - 1; ++it) {
    // K into kv
    gemm_bt<0><<<dim3(MT_B, 2), dim3(256), 0, stream>>>(
        msg, wkT, kv, (float*)nullptr, (const float*)nullptr, 256, 256, MB_PAD);
    // scores, Q chunked
    for (int rowOff = 0; rowOff < MB_PAD; rowOff += qrows) {
      int rows = MB_PAD - rowOff; if (rows > qrows) rows = qrows;
      if (rowOff >= N_BONDS) break;
      gemm_bt<0><<<dim3(rows / 128, 2), dim3(256), 0, stream>>>(
          msg + (size_t)rowOff * 256, wqT, q, (float*)nullptr,
          (const float*)nullptr, 256, 256, MB_PAD);
      score_kernel<<<dim3(rows / 4), dim3(256), 0, stream>>>(
          q, kv, bgraph, attnw, rowOff);
    }
    // V overwrites kv
    gemm_bt<0><<<dim3(MT_B, 2), dim3(256), 0, stream>>>(
        msg, wvT, kv, (float*)nullptr, (const float*)nullptr, 256, 256, MB_PAD);
    weighted_v<<<dim3((N_BONDS + 3) / 4), dim3(256), 0, stream>>>(
        kv, attnw, bgraph, A2);
    // msg = leaky([att|fbonds] @ [Wout;Wemb] + b_emb)
    gemm_bt<1><<<dim3(MT_B, 2), dim3(256), 0, stream>>>(
        A2, wmsgT, msg, (float*)nullptr, bemb, 128, 256, MB_PAD);
  }

  atom_gather<<<dim3(N_ATOMS / 4), dim3(256), 0, stream>>>(msg, agraph, fatoms, apad);
  gemm_bt<3><<<dim3(MT_A, 2), dim3(256), 0, stream>>>(
      apad, wlastT, (unsigned short*)nullptr, out, blast, KL, 256, N_ATOMS);
}

// Round 6
// 2258.198 us; speedup vs baseline: 1.0771x; 1.0771x over previous
//
#include <hip/hip_runtime.h>

#define N_ATOMS 100000
#define N_BONDS 200000
#define NEI 6
#define ITERS 6

#define MB_PAD 200064   // 1563*128
#define MT_B 1563
#define MT_A 782
#define KL 320          // final K (287 padded to 320)
#define KVSTRIDE 768    // bytes per kv row: [K fp8 256 B | V bf16 512 B]

typedef __bf16 bf16x8 __attribute__((ext_vector_type(8)));
typedef float f32x4 __attribute__((ext_vector_type(4)));

__device__ __forceinline__ float b2f(unsigned short u) {
  union { unsigned int i; float f; } x; x.i = ((unsigned int)u) << 16; return x.f;
}
__device__ __forceinline__ unsigned short f2b(float f) {
  union { float f; unsigned int i; } x; x.f = f;
  unsigned int r = (x.i + 0x7FFFu + ((x.i >> 16) & 1u)) >> 16;
  return (unsigned short)r;
}
__device__ __forceinline__ float lrelu(float v) { return v > 0.f ? v : 0.1f * v; }

// ---------------- fp8 e4m3fn encode/decode (HW builtins w/ SW fallback) ----
#if defined(__has_builtin)
#  if __has_builtin(__builtin_amdgcn_cvt_f32_fp8) && __has_builtin(__builtin_amdgcn_cvt_pk_fp8_f32)
#    define HW_FP8 1
#  endif
#endif

__device__ __forceinline__ unsigned char f2e4m3_sw(float f) {
  union { float f; unsigned u; } x; x.f = f;
  unsigned s = (x.u >> 24) & 0x80u;
  unsigned ax = x.u & 0x7FFFFFFFu;
  if (ax >= 0x43E00000u) return (unsigned char)(s | 0x7Eu);  // clamp 448
  if (ax < 0x3A800000u)  return (unsigned char)s;            // < 2^-10 -> 0
  if (ax < 0x3C800000u) {                                    // subnormal: round(a*512)
    union { unsigned u; float f; } a; a.u = ax;
    unsigned n = (unsigned)(a.f * 512.0f + 0.5f);            // 1..8 (8 = min normal)
    return (unsigned char)(s | n);
  }
  unsigned r = ax + 0x0007FFFFu + ((ax >> 20) & 1u);         // RTNE to 3 mant bits
  unsigned e32 = r >> 23;
  unsigned mant = (r >> 20) & 7u;
  int e8 = (int)e32 - 120;
  if (e8 >= 16) return (unsigned char)(s | 0x7Eu);
  return (unsigned char)(s | ((unsigned)e8 << 3) | mant);
}
__device__ __forceinline__ float dec8_sw(unsigned b) {
  unsigned s = (b & 0x80u) << 24;
  unsigned e = (b >> 3) & 0xFu, m = b & 7u;
  if (e) { union { unsigned u; float f; } x; x.u = s | ((e + 120u) << 23) | (m << 20); return x.f; }
  float v = (float)m * 0.001953125f;
  return (b & 0x80u) ? -v : v;
}
#ifdef HW_FP8
__device__ __forceinline__ unsigned char f2e4m3(float f) {
  return (unsigned char)(__builtin_amdgcn_cvt_pk_fp8_f32(f, f, 0, false) & 0xFF);
}
#define DEC0(x) __builtin_amdgcn_cvt_f32_fp8((int)(x), 0)
#define DEC1(x) __builtin_amdgcn_cvt_f32_fp8((int)(x), 1)
#define DEC2(x) __builtin_amdgcn_cvt_f32_fp8((int)(x), 2)
#define DEC3(x) __builtin_amdgcn_cvt_f32_fp8((int)(x), 3)
#else
__device__ __forceinline__ unsigned char f2e4m3(float f) { return f2e4m3_sw(f); }
#define DEC0(x) dec8_sw((x) & 0xFFu)
#define DEC1(x) dec8_sw(((x) >> 8) & 0xFFu)
#define DEC2(x) dec8_sw(((x) >> 16) & 0xFFu)
#define DEC3(x) dec8_sw(((x) >> 24) & 0xFFu)
#endif

// ---------------------------------------------------------------------------
// Weight pack: float32 in -> bf16 B^T copies (row-major [N,K]).
// wkvT [512][256]: n<256 -> Wk col n; else Wv col n-256  (fused KV GEMM)
// wqT [256][256]; wmsgT [256][128] (k<64: Wout, 64..100: Wemb, pad 0)
// wlastT [256][320] (k<256: W_last[31+k], 256..286: W_last[k-256], pad 0)
// ---------------------------------------------------------------------------
__global__ __launch_bounds__(256) void pack_weights(
    const float* __restrict__ Wq, const float* __restrict__ Wk,
    const float* __restrict__ Wv, const float* __restrict__ Wemb,
    const float* __restrict__ Wout, const float* __restrict__ Wlast,
    unsigned short* __restrict__ wkvT, unsigned short* __restrict__ wqT,
    unsigned short* __restrict__ wmsgT, unsigned short* __restrict__ wlastT)
{
  int t = blockIdx.x * 256 + threadIdx.x;   // grid = 512 blocks -> t < 131072
  {
    int n = t >> 8, k = t & 255;
    wkvT[t] = f2b((n < 256) ? Wk[k * 256 + n] : Wv[k * 256 + (n - 256)]);
  }
  if (t < 65536) {
    int n = t >> 8, k = t & 255;
    wqT[t] = f2b(Wq[k * 256 + n]);
  }
  if (t < 32768) {
    int n = t >> 7, k = t & 127;
    float v = 0.f;
    if (k < 64)       v = Wout[k * 256 + n];
    else if (k < 101) v = Wemb[(k - 64) * 256 + n];
    wmsgT[t] = f2b(v);
  }
  if (t < 256 * KL) {
    int n = t / KL, k = t % KL;
    float v = 0.f;
    if (k < 256)      v = Wlast[(31 + k) * 256 + n];
    else if (k < 287) v = Wlast[(k - 256) * 256 + n];
    wlastT[t] = f2b(v);
  }
}

// A2 [MB_PAD][128]: cols 0..63 = 0 (att slot), 64..100 = bf16(fbonds), rest 0
__global__ __launch_bounds__(256) void pack_bonds(
    const float* __restrict__ fbonds, unsigned short* __restrict__ A2)
{
  int t = blockIdx.x * 256 + threadIdx.x;
  int r = t >> 7, c = t & 127;
  float v = 0.f;
  if (c >= 64 && c < 101 && r < N_BONDS) v = fbonds[r * 37 + (c - 64)];
  A2[t] = f2b(v);
}

// ---------------------------------------------------------------------------
// m97-style 128x128 bf16 GEMM. A [*,K] row-major bf16, BT [N,K] row-major bf16.
// EP: 0 plain bf16 store; 1 +bias Xf[col] leaky -> bf16;
//     3 +bias Xf[col] leaky, row<Mreal guard -> FLOAT out
//     4 kv epilogue: col<256 -> fp8 @ row*768+col; else bf16 @ row*768+256+(col-256)*2
// ---------------------------------------------------------------------------
template<int EP>
__global__ __launch_bounds__(256) void gemm_bt(
    const unsigned short* __restrict__ A,
    const unsigned short* __restrict__ BT,
    unsigned short* __restrict__ C0,
    float* __restrict__ Fout,
    const float* __restrict__ Xf,
    int K, int N, int Mreal)
{
  __shared__ __align__(16) unsigned short As[128 * 64];
  __shared__ __align__(16) unsigned short Bs[128 * 64];
  const int tid  = threadIdx.x;
  const int wave = tid >> 6, lane = tid & 63;
  const int wr = wave >> 1, wc = wave & 1;
  const int lhi = lane >> 4, llo = lane & 15;
  const int mBase = blockIdx.x * 128;
  const int nBase = blockIdx.y * 128;
  const int crow = tid >> 3, ccol = tid & 7;   // per-lane staging coords

  f32x4 acc[4][4];
  #pragma unroll
  for (int i = 0; i < 4; ++i)
    #pragma unroll
    for (int j = 0; j < 4; ++j)
      acc[i][j] = f32x4{0.f, 0.f, 0.f, 0.f};

  for (int k0 = 0; k0 < K; k0 += 64) {
    __syncthreads();
    #pragma unroll
    for (int r = 0; r < 4; ++r) {
      const unsigned short* ga =
          A + (size_t)(mBase + r * 32 + crow) * K + (k0 + ccol * 8);
      __builtin_amdgcn_global_load_lds(
          (const __attribute__((address_space(1))) void*)ga,
          (__attribute__((address_space(3))) void*)(As + r * 2048 + wave * 512), 16, 0, 0);
      const unsigned short* gb =
          BT + (size_t)(nBase + r * 32 + crow) * K + (k0 + ccol * 8);
      __builtin_amdgcn_global_load_lds(
          (const __attribute__((address_space(1))) void*)gb,
          (__attribute__((address_space(3))) void*)(Bs + r * 2048 + wave * 512), 16, 0, 0);
    }
    __syncthreads();
    #pragma unroll
    for (int ks = 0; ks < 2; ++ks) {
      bf16x8 af[4], bfv[4];
      #pragma unroll
      for (int i = 0; i < 4; ++i)
        af[i] = *reinterpret_cast<const bf16x8*>(&As[(wr * 64 + i * 16 + llo) * 64 + ks * 32 + lhi * 8]);
      #pragma unroll
      for (int j = 0; j < 4; ++j)
        bfv[j] = *reinterpret_cast<const bf16x8*>(&Bs[(wc * 64 + j * 16 + llo) * 64 + ks * 32 + lhi * 8]);
      #pragma unroll
      for (int i = 0; i < 4; ++i)
        #pragma unroll
        for (int j = 0; j < 4; ++j)
          acc[i][j] = __builtin_amdgcn_mfma_f32_16x16x32_bf16(af[i], bfv[j], acc[i][j], 0, 0, 0);
    }
  }

  #pragma unroll
  for (int i = 0; i < 4; ++i) {
    #pragma unroll
    for (int j = 0; j < 4; ++j) {
      const int col = nBase + wc * 64 + j * 16 + llo;
      #pragma unroll
      for (int r = 0; r < 4; ++r) {
        const int row = mBase + wr * 64 + i * 16 + lhi * 4 + r;
        const float v = acc[i][j][r];
        if (EP == 0) {
          C0[(size_t)row * N + col] = f2b(v);
        } else if (EP == 1) {
          C0[(size_t)row * N + col] = f2b(lrelu(v + Xf[col]));
        } else if (EP == 3) {
          if (row < Mreal) Fout[(size_t)row * N + col] = lrelu(v + Xf[col]);
        } else {  // EP == 4: mixed fp8-K / bf16-V strided kv row
          unsigned char* kvb = (unsigned char*)C0;
          if (nBase < 256) {
            kvb[(size_t)row * KVSTRIDE + col] = f2e4m3(v);
          } else {
            *(unsigned short*)(kvb + (size_t)row * KVSTRIDE + 256 +
                               (size_t)(col - 256) * 2) = f2b(v);
          }
        }
      }
    }
  }
}

// ---------------------------------------------------------------------------
// Merged attention: one wave per bond. Gathers unified kv rows (768 B):
// K fp8 [256 B] + V bf16 [512 B]. lane l: head h=l>>4, dims l*4..l*4+3.
// scores -> softmax -> weighted V -> head-mean -> A2[wid][0..63].
// ---------------------------------------------------------------------------
__global__ __launch_bounds__(256) void attn_merged(
    const unsigned short* __restrict__ q,
    const unsigned char* __restrict__ kv,
    const int* __restrict__ bgraph,
    unsigned short* __restrict__ A2,
    int rowOff)
{
  const int wid  = rowOff + blockIdx.x * 4 + (threadIdx.x >> 6);
  const int lane = threadIdx.x & 63;
  if (wid >= N_BONDS) return;

  const ushort4 qu = *reinterpret_cast<const ushort4*>(
      q + (size_t)(wid - rowOff) * 256 + lane * 4);
  const float q0 = b2f(qu.x), q1 = b2f(qu.y), q2 = b2f(qu.z), q3 = b2f(qu.w);

  int bn[NEI];
  #pragma unroll
  for (int n = 0; n < NEI; ++n) bn[n] = bgraph[wid * NEI + n];

  unsigned kdw[NEI]; ushort4 vu[NEI];
  #pragma unroll
  for (int n = 0; n < NEI; ++n) {
    const unsigned char* base = kv + (size_t)bn[n] * KVSTRIDE;
    kdw[n] = *reinterpret_cast<const unsigned*>(base + lane * 4);
    vu[n]  = *reinterpret_cast<const ushort4*>(base + 256 + lane * 8);
  }

  float sc[NEI];
  #pragma unroll
  for (int n = 0; n < NEI; ++n) {
    float p = q0 * DEC0(kdw[n]) + q1 * DEC1(kdw[n]) +
              q2 * DEC2(kdw[n]) + q3 * DEC3(kdw[n]);
    p += __shfl_xor(p, 1); p += __shfl_xor(p, 2);
    p += __shfl_xor(p, 4); p += __shfl_xor(p, 8);   // sum over 16-lane head group
    sc[n] = p * 0.125f + (bn[n] != 0 ? 0.f : -1e7f);
  }
  float m = sc[0];
  #pragma unroll
  for (int n = 1; n < NEI; ++n) m = fmaxf(m, sc[n]);
  float e[NEI], s = 0.f;
  #pragma unroll
  for (int n = 0; n < NEI; ++n) { e[n] = __expf(sc[n] - m); s += e[n]; }
  const float inv = 1.f / s;

  float o0 = 0, o1 = 0, o2 = 0, o3 = 0;
  #pragma unroll
  for (int n = 0; n < NEI; ++n) {
    const float a = e[n] * inv;
    o0 += a * b2f(vu[n].x); o1 += a * b2f(vu[n].y);
    o2 += a * b2f(vu[n].z); o3 += a * b2f(vu[n].w);
  }
  o0 += __shfl_xor(o0, 16); o0 += __shfl_xor(o0, 32);
  o1 += __shfl_xor(o1, 16); o1 += __shfl_xor(o1, 32);
  o2 += __shfl_xor(o2, 16); o2 += __shfl_xor(o2, 32);
  o3 += __shfl_xor(o3, 16); o3 += __shfl_xor(o3, 32);
  if (lane < 16) {
    ushort4 ov;
    ov.x = f2b(o0 * 0.25f); ov.y = f2b(o1 * 0.25f);
    ov.z = f2b(o2 * 0.25f); ov.w = f2b(o3 * 0.25f);
    *reinterpret_cast<ushort4*>(A2 + (size_t)wid * 128 + lane * 4) = ov;
  }
}

// One wave per atom: nei_sum (fp32 accum) -> apad [MA_PAD][320]
// = [nei_sum(256) | bf16(fatoms)(31) | zeros]
__global__ __launch_bounds__(256) void atom_gather(
    const unsigned short* __restrict__ msg,
    const int* __restrict__ agraph,
    const float* __restrict__ fatoms,
    unsigned short* __restrict__ apad)
{
  const int aid  = blockIdx.x * 4 + (threadIdx.x >> 6);
  const int lane = threadIdx.x & 63;
  if (aid >= N_ATOMS) return;
  float s0 = 0, s1 = 0, s2 = 0, s3 = 0;
  #pragma unroll
  for (int n = 0; n < NEI; ++n) {
    const int b = agraph[aid * NEI + n];
    const ushort4 u = *reinterpret_cast<const ushort4*>(msg + (size_t)b * 256 + lane * 4);
    s0 += b2f(u.x); s1 += b2f(u.y); s2 += b2f(u.z); s3 += b2f(u.w);
  }
  ushort4 ov; ov.x = f2b(s0); ov.y = f2b(s1); ov.z = f2b(s2); ov.w = f2b(s3);
  *reinterpret_cast<ushort4*>(apad + (size_t)aid * KL + lane * 4) = ov;
  apad[(size_t)aid * KL + 256 + lane] =
      (lane < 31) ? f2b(fatoms[(size_t)aid * 31 + lane]) : (unsigned short)0;
}

// Diagnostic: zero output, out[0] = 10000 + ws_MB (distinguishable absmax)
__global__ __launch_bounds__(256) void diag_out(float* out, int n, float code) {
  int t = blockIdx.x * 256 + threadIdx.x;
  if (t < n) out[t] = (t == 0) ? code : 0.f;
}

extern "C" void kernel_launch(void* const* d_in, const int* in_sizes, int n_in,
                              void* d_out, int out_size, void* d_ws, size_t ws_size,
                              hipStream_t stream) {
  const float* fatoms = (const float*)d_in[0];
  const float* fbonds = (const float*)d_in[1];
  const int* agraph   = (const int*)d_in[2];
  const int* bgraph   = (const int*)d_in[3];
  // d_in[4] lig_scope: unused by the reference computation
  const float* Wemb   = (const float*)d_in[5];
  const float* bemb   = (const float*)d_in[6];
  const float* Wq     = (const float*)d_in[7];
  const float* Wk     = (const float*)d_in[8];
  const float* Wv     = (const float*)d_in[9];
  const float* Wout   = (const float*)d_in[10];
  const float* Wlast  = (const float*)d_in[11];
  const float* blast  = (const float*)d_in[12];
  float* out          = (float*)d_out;

  char* ws = (char*)d_ws;
  size_t off = 0;
  auto alloc = [&](size_t bytes) {
    char* p = ws + off; off += (bytes + 511) & ~(size_t)511; return p;
  };
  unsigned short* msg    = (unsigned short*)alloc((size_t)MB_PAD * 256 * 2);
  unsigned char*  kv     = (unsigned char*)alloc((size_t)MB_PAD * KVSTRIDE); // atom-A alias
  unsigned short* A2     = (unsigned short*)alloc((size_t)MB_PAD * 128 * 2);
  unsigned short* wkvT   = (unsigned short*)alloc((size_t)512 * 256 * 2);
  unsigned short* wqT    = (unsigned short*)alloc((size_t)256 * 256 * 2);
  unsigned short* wmsgT  = (unsigned short*)alloc((size_t)256 * 128 * 2);
  unsigned short* wlastT = (unsigned short*)alloc((size_t)256 * KL * 2);
  unsigned short* apad   = (unsigned short*)kv;  // kv dead after loop (64.1 <= 153.6 MB)

  // adaptive Q chunk from leftover workspace (q row = 256 bf16 = 512 B)
  long long remain = (long long)ws_size - (long long)off;
  int qrows = 0;
  if (remain >= 128 * 512) {
    long long r = remain / 512;
    if (r > MB_PAD) r = MB_PAD;
    qrows = (int)(r & ~127LL);
  }
  unsigned short* q = (unsigned short*)(ws + off);

  if (qrows < 128) {   // workspace too small: diagnostic
    diag_out<<<dim3((out_size + 255) / 256), dim3(256), 0, stream>>>(
        out, out_size, 10000.f + (float)(ws_size >> 20));
    return;
  }

  pack_weights<<<dim3(512), dim3(256), 0, stream>>>(
      Wq, Wk, Wv, Wemb, Wout, Wlast, wkvT, wqT, wmsgT, wlastT);
  pack_bonds<<<dim3(MB_PAD * 128 / 256), dim3(256), 0, stream>>>(fbonds, A2);

  // initial message: att cols of A2 are zero -> msg = leaky(fbonds@Wemb + b)
  gemm_bt<1><<<dim3(MT_B, 2), dim3(256), 0, stream>>>(
      A2, wmsgT, msg, (float*)nullptr, bemb, 128, 256, MB_PAD);

  for (int it = 0; it < ITERS - 1; ++it) {
    // chunk-0 Q first (so kv is L3-hot when attn chunk 0 runs)
    int rows0 = MB_PAD < qrows ? MB_PAD : qrows;
    gemm_bt<0><<<dim3(rows0 / 128, 2), dim3(256), 0, stream>>>(
        msg, wqT, q, (float*)nullptr, (const float*)nullptr, 256, 256, MB_PAD);
    // fused KV GEMM: [K-fp8 | V-bf16] strided rows
    gemm_bt<4><<<dim3(MT_B, 4), dim3(256), 0, stream>>>(
        msg, wkvT, (unsigned short*)kv, (float*)nullptr, (const float*)nullptr,
        256, 512, MB_PAD);
    attn_merged<<<dim3(rows0 / 4), dim3(256), 0, stream>>>(q, kv, bgraph, A2, 0);
    for (int rowOff = qrows; rowOff < N_BONDS; rowOff += qrows) {
      int rows = MB_PAD - rowOff; if (rows > qrows) rows = qrows;
      gemm_bt<0><<<dim3(rows / 128, 2), dim3(256), 0, stream>>>(
          msg + (size_t)rowOff * 256, wqT, q, (float*)nullptr,
          (const float*)nullptr, 256, 256, MB_PAD);
      attn_merged<<<dim3(rows / 4), dim3(256), 0, stream>>>(
          q, kv, bgraph, A2, rowOff);
    }
    // msg = leaky([att|fbonds] @ [Wout;Wemb] + b_emb)
    gemm_bt<1><<<dim3(MT_B, 2), dim3(256), 0, stream>>>(
        A2, wmsgT, msg, (float*)nullptr, bemb, 128, 256, MB_PAD);
  }

  atom_gather<<<dim3(N_ATOMS / 4), dim3(256), 0, stream>>>(msg, agraph, fatoms, apad);
  gemm_bt<3><<<dim3(MT_A, 2), dim3(256), 0, stream>>>(
      apad, wlastT, (unsigned short*)nullptr, out, blast, KL, 256, N_ATOMS);
}